// Round 8
// baseline (50.657 us; speedup 1.0000x reference)
//
#include <hip/hip_runtime.h>
#include <hip/hip_bf16.h>
#include <math.h>

#define BB 4
#define TT 4096
#define CC 1024
#define HS 64
#define WIN 512
#define NROW (BB*TT)

typedef float f32x4 __attribute__((ext_vector_type(4)));
typedef short bf16x8 __attribute__((ext_vector_type(8)));

#define MFMA16(a, b, c) __builtin_amdgcn_mfma_f32_16x16x32_bf16((a), (b), (c), 0, 0, 0)

#define GLOAD_LDS(gp, lp) __builtin_amdgcn_global_load_lds( \
    (const __attribute__((address_space(1))) void*)(gp), \
    (__attribute__((address_space(3))) void*)(lp), 16, 0, 0)

__device__ inline unsigned short f2b(float f) {
  union { __hip_bfloat16 h; unsigned short u; } v;
  v.h = __float2bfloat16(f);   // HW RNE convert
  return v.u;
}

// ---------------- pack W into MFMA B-fragment order (bf16) ----------------
// wp flat index: ((kt*12 + nb)*64 + lane)*8 + j
// holds W[k = kt*32 + (lane>>4)*8 + j][n = nb*16 + (lane&15)],
// n: 0..63 = w_query, 64..127 = w_key, 128..191 = w_value
__global__ __launch_bounds__(256) void pack_w_kernel(
    const float* __restrict__ wq, const float* __restrict__ wk,
    const float* __restrict__ wv, unsigned short* __restrict__ wp)
{
  int t = blockIdx.x * 256 + threadIdx.x;   // 49152 threads
  int kg = t / 48;                          // 0..1023  (k index)
  int nq = t % 48;                          // 4-col group
  int n0 = nq * 4;
  int m  = n0 >> 6;
  int c  = n0 & 63;
  const float* w = (m == 0) ? wq : (m == 1) ? wk : wv;
  float4 v = *(const float4*)&w[(size_t)kg * HS + c];
  int kt = kg >> 5;
  int hi = (kg >> 3) & 3;
  int j  = kg & 7;
  float vals[4] = {v.x, v.y, v.z, v.w};
  #pragma unroll
  for (int i = 0; i < 4; ++i) {
    int n  = n0 + i;
    int nb = n >> 4;
    int rl = n & 15;
    int lane = hi * 16 + rl;
    wp[((size_t)(kt * 12 + nb) * 64 + lane) * 8 + j] = f2b(vals[i]);
  }
}

// ---------------- Projection via MFMA: [q|k|v] = x @ W ----------------
// BM=64, 256 blocks x 512 threads (8 waves = 4 col-quarters x 2 row-halves).
// wp re-read traffic halved vs BM=32. x LDS layout [region(ktl,gg)][kq][row]:
// staging keeps 64B/row coalesced global segments; compute ds_read_b128 is
// piecewise lane-contiguous (conflict-free). Counted-vmcnt 2-deep pipeline.
__global__ __launch_bounds__(512) void proj_mfma_kernel(
    const float* __restrict__ x, const unsigned short* __restrict__ wp,
    unsigned short* __restrict__ q_ws, unsigned short* __restrict__ k_ws,
    unsigned short* __restrict__ vt_ws)
{
  __shared__ unsigned char xbuf[2][16384];   // [buf][region(8)*2048]
  __shared__ unsigned char wbuf[2][24576];   // [buf][slot(1536)*16B]

  const int tid = threadIdx.x;
  const int l   = tid & 63;
  const int wid = tid >> 6;     // 0..7
  const int cq  = wid & 3;      // col quarter (3 nb)
  const int rh  = wid >> 2;     // row half (2 gg)
  const int rl  = l & 15;
  const int hi  = l >> 4;
  const int r0  = blockIdx.x * 64;

  f32x4 acc[2][3];
  #pragma unroll
  for (int g = 0; g < 2; ++g)
    #pragma unroll
    for (int j = 0; j < 3; ++j) acc[g][j] = (f32x4){0.f, 0.f, 0.f, 0.f};

  // x slot s (0..1023): region = s>>7 (ktl = region>>2, gg = region&3),
  //   u = s&127: row = r0+gg*16+(u&15), col = ks*64+ktl*32+(u>>4)*4.
  //   One wave-instr = 16 rows x 64B contiguous segments (coalesced).
  // w slot t (0..1535): straight fragment stream.
#define STAGE(KS, BUF) { \
    _Pragma("unroll") \
    for (int r = 0; r < 2; ++r) { \
      int s   = r * 512 + tid; \
      int reg = s >> 7; \
      int u   = s & 127; \
      int ktl = reg >> 2; \
      int gg  = reg & 3; \
      int row = r0 + gg * 16 + (u & 15); \
      int col = (KS) * 64 + ktl * 32 + (u >> 4) * 4; \
      GLOAD_LDS(x + (size_t)row * CC + col, &xbuf[BUF][s * 16]); \
    } \
    const unsigned short* wsrc = wp + (size_t)(KS) * 12288; \
    _Pragma("unroll") \
    for (int r = 0; r < 3; ++r) { \
      int t = r * 512 + tid; \
      GLOAD_LDS(wsrc + t * 8, &wbuf[BUF][t * 16]); \
    } }

  STAGE(0, 0)
  STAGE(1, 1)

  for (int ks = 0; ks < 16; ++ks) {
    const int cur = ks & 1;
    // 5 loads/thread/stage; keep next buffer's 5 in flight.
    if (ks < 15) { asm volatile("s_waitcnt vmcnt(5)" ::: "memory"); }
    else         { asm volatile("s_waitcnt vmcnt(0)" ::: "memory"); }
    __builtin_amdgcn_sched_barrier(0);
    __builtin_amdgcn_s_barrier();

    // ---- compute from buffers[cur] ----
    #pragma unroll
    for (int ktl = 0; ktl < 2; ++ktl) {
      bf16x8 afr[2];
      #pragma unroll
      for (int g = 0; g < 2; ++g) {
        int gg  = rh * 2 + g;
        int reg = ktl * 4 + gg;
        const unsigned char* base =
            &xbuf[cur][reg * 2048 + (l >> 4) * 512 + (l & 15) * 16];
        f32x4 a0 = *(const f32x4*)base;
        f32x4 a1 = *(const f32x4*)(base + 256);
        bf16x8 af;
        af[0] = (short)f2b(a0[0]); af[1] = (short)f2b(a0[1]);
        af[2] = (short)f2b(a0[2]); af[3] = (short)f2b(a0[3]);
        af[4] = (short)f2b(a1[0]); af[5] = (short)f2b(a1[1]);
        af[6] = (short)f2b(a1[2]); af[7] = (short)f2b(a1[3]);
        afr[g] = af;
      }
      #pragma unroll
      for (int j = 0; j < 3; ++j) {
        bf16x8 wf = *(const bf16x8*)&wbuf[cur][((ktl * 12 + cq * 3 + j) * 64 + l) * 16];
        acc[0][j] = MFMA16(afr[0], wf, acc[0][j]);
        acc[1][j] = MFMA16(afr[1], wf, acc[1][j]);
      }
    }

    if (ks < 14) {
      // WAR guard: my LDS reads done, then all waves done, then overwrite.
      asm volatile("s_waitcnt lgkmcnt(0)" ::: "memory");
      __builtin_amdgcn_sched_barrier(0);
      __builtin_amdgcn_s_barrier();
      STAGE(ks + 2, cur)
    }
  }
#undef STAGE

  // ---- store: nb 0..3 -> q, 4..7 -> k, 8..11 -> v (transposed per 64-chunk)
  #pragma unroll
  for (int g = 0; g < 2; ++g) {
    int rb = r0 + rh * 32 + g * 16;
    #pragma unroll
    for (int j = 0; j < 3; ++j) {
      int nb = cq * 3 + j;
      if (nb < 8) {
        unsigned short* dst = (nb < 4) ? q_ws : k_ws;
        int c = (nb & 3) * 16 + rl;
        #pragma unroll
        for (int r = 0; r < 4; ++r) {
          int row = rb + hi * 4 + r;
          dst[(size_t)row * HS + c] = f2b(acc[g][j][r]);
        }
      } else {
        int ch   = rb >> 6;
        int key0 = (rb & 63) + hi * 4;
        int d = (nb - 8) * 16 + rl;
        unsigned u0 = (unsigned)f2b(acc[g][j][0]) | ((unsigned)f2b(acc[g][j][1]) << 16);
        unsigned u1 = (unsigned)f2b(acc[g][j][2]) | ((unsigned)f2b(acc[g][j][3]) << 16);
        uint2 uu; uu.x = u0; uu.y = u1;
        *(uint2*)(vt_ws + (size_t)ch * 4096 + d * 64 + key0) = uu;
      }
    }
  }
}

// ---------------- Sliding-window flash attention via MFMA ----------------
// grid 256 blocks (b, 64-q tile) x 256 threads (4 waves, 16 q-rows each).
// Swapped QK^T (S^T = K @ Q^T) -> softmax lane-local; P via wave-private LDS;
// PV with V^T staged swizzled.
__global__ __launch_bounds__(256) void attn_mfma_kernel(
    const unsigned short* __restrict__ q_ws, const unsigned short* __restrict__ k_ws,
    const unsigned short* __restrict__ vt_ws, float* __restrict__ out)
{
  __shared__ uint4 smem4[1600];                 // 25600 B
  unsigned char* smem = (unsigned char*)smem4;  // K:[0,8K) Vt:[8K,16K) P:16K+

  const int tid = threadIdx.x;
  const int l   = tid & 63;
  const int wid = tid >> 6;
  const int rl  = l & 15;
  const int hi  = l >> 4;
  const int b   = blockIdx.x >> 6;
  const int qt  = blockIdx.x & 63;
  const int t0  = qt * 64;
  const int t0w = t0 + wid * 16;

  // Q B-fragments (held in registers): lane = q row t0w+rl, d = hi*8+j (+32)
  const unsigned short* qrow = q_ws + (size_t)(b * TT + t0w + rl) * HS;
  bf16x8 qb0 = *(const bf16x8*)(qrow + hi * 8);
  bf16x8 qb1 = *(const bf16x8*)(qrow + 32 + hi * 8);

  f32x4 oacc[4];
  #pragma unroll
  for (int i = 0; i < 4; ++i) oacc[i] = (f32x4){0.f, 0.f, 0.f, 0.f};
  float m_run = -INFINITY, l_run = 0.f;

  int s_lo = t0 - WIN; if (s_lo < 0) s_lo = 0;
  unsigned char* pbase = smem + 16384 + wid * 2304 + rl * 144;

  for (int sc = s_lo; sc < t0 + 64; sc += 64) {
    __syncthreads();
    // ---- stage K and Vt chunk (64x64 bf16 each), XOR-swizzled rows ----
    {
      const unsigned short* kg = k_ws + (size_t)(b * TT + sc) * HS;
      const unsigned short* vg = vt_ws + (size_t)((b * TT + sc) >> 6) * 4096;
      #pragma unroll
      for (int i = 0; i < 2; ++i) {
        int idx = tid + i * 256;
        int row = idx >> 3;
        int c16 = idx & 7;
        uint4 kv = *(const uint4*)(kg + row * 64 + c16 * 8);
        uint4 vv = *(const uint4*)(vg + row * 64 + c16 * 8);
        *(uint4*)(smem + row * 128 + ((c16 ^ (row & 7)) * 16)) = kv;
        *(uint4*)(smem + 8192 + row * 128 + ((c16 ^ (row & 7)) * 16)) = vv;
      }
    }
    __syncthreads();

    // ---- S^T = K @ Q^T : 4 key-block fragments ----
    f32x4 sacc[4];
    #pragma unroll
    for (int i = 0; i < 4; ++i) sacc[i] = (f32x4){0.f, 0.f, 0.f, 0.f};
    #pragma unroll
    for (int kb = 0; kb < 4; ++kb) {
      int row = kb * 16 + rl;
      unsigned char* kr = smem + row * 128;
      bf16x8 k0 = *(const bf16x8*)(kr + (((hi) ^ (row & 7)) * 16));
      bf16x8 k1 = *(const bf16x8*)(kr + (((4 + hi) ^ (row & 7)) * 16));
      sacc[kb] = MFMA16(k0, qb0, sacc[kb]);
      sacc[kb] = MFMA16(k1, qb1, sacc[kb]);
    }

    // ---- mask + scale + online softmax (lane owns one q = t0w+rl) ----
    const int tg = t0w + rl;
    float p[16];
    float tm = -INFINITY;
    bool full = (sc + 63 <= t0w) && (sc >= t0w - 496);
    #pragma unroll
    for (int kb = 0; kb < 4; ++kb)
      #pragma unroll
      for (int r = 0; r < 4; ++r) {
        float v = sacc[kb][r] * 0.125f;
        if (!full) {
          int key = sc + kb * 16 + hi * 4 + r;
          int diff = tg - key;
          v = (diff >= 0 && diff < WIN) ? v : -INFINITY;
        }
        p[kb * 4 + r] = v;
        tm = fmaxf(tm, v);
      }
    tm = fmaxf(tm, __shfl_xor(tm, 16));
    tm = fmaxf(tm, __shfl_xor(tm, 32));
    float m_new = fmaxf(m_run, tm);
    float fac  = (m_new == -INFINITY) ? 1.f : __expf(m_run - m_new);
    float msub = (m_new == -INFINITY) ? 0.f : m_new;
    float lsum = 0.f;
    #pragma unroll
    for (int i = 0; i < 16; ++i) { p[i] = __expf(p[i] - msub); lsum += p[i]; }
    lsum += __shfl_xor(lsum, 16);
    lsum += __shfl_xor(lsum, 32);
    l_run = l_run * fac + lsum;
    m_run = m_new;

    // ---- P -> wave-private LDS (row q=rl, stride 144 B) ----
    #pragma unroll
    for (int kb = 0; kb < 4; ++kb) {
      unsigned u0 = (unsigned)f2b(p[kb * 4 + 0]) | ((unsigned)f2b(p[kb * 4 + 1]) << 16);
      unsigned u1 = (unsigned)f2b(p[kb * 4 + 2]) | ((unsigned)f2b(p[kb * 4 + 3]) << 16);
      uint2 uu; uu.x = u0; uu.y = u1;
      *(uint2*)(pbase + kb * 32 + hi * 8) = uu;
    }

    // ---- rescale O by fac (redistribute to PV C-layout q = hi*4+r) ----
    #pragma unroll
    for (int r = 0; r < 4; ++r) {
      float fr = __shfl(fac, (l & 48) | (hi * 4 + r));
      oacc[0][r] *= fr; oacc[1][r] *= fr; oacc[2][r] *= fr; oacc[3][r] *= fr;
    }

    // ---- PV: O[q][d] += P @ V ----
    bf16x8 pa0 = *(const bf16x8*)(pbase + hi * 16);
    bf16x8 pa1 = *(const bf16x8*)(pbase + 64 + hi * 16);
    #pragma unroll
    for (int f = 0; f < 4; ++f) {
      int d = f * 16 + rl;
      unsigned char* vr = smem + 8192 + d * 128;
      bf16x8 v0 = *(const bf16x8*)(vr + (((hi) ^ (d & 7)) * 16));
      bf16x8 v1 = *(const bf16x8*)(vr + (((4 + hi) ^ (d & 7)) * 16));
      oacc[f] = MFMA16(pa0, v0, oacc[f]);
      oacc[f] = MFMA16(pa1, v1, oacc[f]);
    }
  }

  // ---- epilogue: normalize and store f32 ----
  float inv = 1.f / l_run;   // softmax layout (q = rl)
  #pragma unroll
  for (int r = 0; r < 4; ++r) {
    float ir = __shfl(inv, (l & 48) | (hi * 4 + r));
    int row = b * TT + t0w + hi * 4 + r;
    #pragma unroll
    for (int f = 0; f < 4; ++f)
      out[(size_t)row * HS + f * 16 + rl] = oacc[f][r] * ir;
  }
}

extern "C" void kernel_launch(void* const* d_in, const int* in_sizes, int n_in,
                              void* d_out, int out_size, void* d_ws, size_t ws_size,
                              hipStream_t stream) {
  // setup_inputs dict order: x, w_key, w_query, w_value
  const float* x  = (const float*)d_in[0];
  const float* wk = (const float*)d_in[1];
  const float* wq = (const float*)d_in[2];
  const float* wv = (const float*)d_in[3];
  float* out = (float*)d_out;

  unsigned short* wp    = (unsigned short*)d_ws;        // 196608 el = 384 KB
  unsigned short* q_ws  = wp + 196608;                  // 2 MB
  unsigned short* k_ws  = q_ws + (size_t)NROW * HS;     // 2 MB
  unsigned short* vt_ws = k_ws + (size_t)NROW * HS;     // 2 MB

  pack_w_kernel<<<192, 256, 0, stream>>>(wq, wk, wv, wp);
  proj_mfma_kernel<<<NROW / 64, 512, 0, stream>>>(x, wp, q_ws, k_ws, vt_ws);
  attn_mfma_kernel<<<BB * (TT / 64), 256, 0, stream>>>(q_ws, k_ws, vt_ws, out);
}

// Round 9
// 45.556 us; speedup vs baseline: 1.1120x; 1.1120x over previous
//
#include <hip/hip_runtime.h>
#include <hip/hip_bf16.h>
#include <math.h>

#define BB 4
#define TT 4096
#define CC 1024
#define HS 64
#define WIN 512
#define NROW (BB*TT)

typedef float f32x4 __attribute__((ext_vector_type(4)));
typedef short bf16x8 __attribute__((ext_vector_type(8)));

#define MFMA16(a, b, c) __builtin_amdgcn_mfma_f32_16x16x32_bf16((a), (b), (c), 0, 0, 0)

#define GLOAD_LDS(gp, lp) __builtin_amdgcn_global_load_lds( \
    (const __attribute__((address_space(1))) void*)(gp), \
    (__attribute__((address_space(3))) void*)(lp), 16, 0, 0)

__device__ inline unsigned short f2b(float f) {
  union { __hip_bfloat16 h; unsigned short u; } v;
  v.h = __float2bfloat16(f);   // HW RNE convert
  return v.u;
}

// ---------------- pack W into MFMA B-fragment order (bf16) ----------------
// wp flat index: ((kt*12 + nb)*64 + lane)*8 + j
// holds W[k = kt*32 + (lane>>4)*8 + j][n = nb*16 + (lane&15)],
// n: 0..63 = w_query, 64..127 = w_key, 128..191 = w_value
__global__ __launch_bounds__(256) void pack_w_kernel(
    const float* __restrict__ wq, const float* __restrict__ wk,
    const float* __restrict__ wv, unsigned short* __restrict__ wp)
{
  int t = blockIdx.x * 256 + threadIdx.x;   // 49152 threads
  int kg = t / 48;                          // 0..1023  (k index)
  int nq = t % 48;                          // 4-col group
  int n0 = nq * 4;
  int m  = n0 >> 6;
  int c  = n0 & 63;
  const float* w = (m == 0) ? wq : (m == 1) ? wk : wv;
  float4 v = *(const float4*)&w[(size_t)kg * HS + c];
  int kt = kg >> 5;
  int hi = (kg >> 3) & 3;
  int j  = kg & 7;
  float vals[4] = {v.x, v.y, v.z, v.w};
  #pragma unroll
  for (int i = 0; i < 4; ++i) {
    int n  = n0 + i;
    int nb = n >> 4;
    int rl = n & 15;
    int lane = hi * 16 + rl;
    wp[((size_t)(kt * 12 + nb) * 64 + lane) * 8 + j] = f2b(vals[i]);
  }
}

// ---------------- Projection via MFMA: [q|k|v] = x @ W ----------------
// 512 blocks x 256 threads (4 waves, each 32 rows x 48 cols). BK=64, 16 steps.
// x: row-CONTIGUOUS staging (wave-instr = 4 rows x 256B = 8 lines) into
//    3-deep LDS ring; source-pre-swizzled (chunk cg = cpos ^ ((row&7)<<1)) so
//    swizzled ds_read_b128 fragment reads are bank-conflict-free.
// W: direct global->register (fragment-packed, contiguous 1KB wave-loads),
//    2-step prefetch into statically-named wA/wB. No W LDS round-trip.
// Counted vmcnt(6): keeps [SX(ks+2), LW(ks+1)] in flight across barriers.
__global__ __launch_bounds__(256) void proj_mfma_kernel(
    const float* __restrict__ x, const unsigned short* __restrict__ wp,
    unsigned short* __restrict__ q_ws, unsigned short* __restrict__ k_ws,
    unsigned short* __restrict__ vt_ws)
{
  __shared__ unsigned char xbuf[3][8192];   // [buf][row(32)*256B]

  const int tid = threadIdx.x;
  const int l   = tid & 63;
  const int cq  = tid >> 6;     // wave = col quarter (3 nb)
  const int rl  = l & 15;
  const int hi  = l >> 4;
  const int r0  = blockIdx.x * 32;

  f32x4 acc[2][3];
  #pragma unroll
  for (int g = 0; g < 2; ++g)
    #pragma unroll
    for (int j = 0; j < 3; ++j) acc[g][j] = (f32x4){0.f, 0.f, 0.f, 0.f};

  // x stage: slot s (0..511): row = s>>4, cpos = s&15 (16B chunks);
  // LDS linear, global chunk pre-swizzled. Wave-instr = 4 rows x 256B contig.
#define SX(KS, BUF) { \
    _Pragma("unroll") \
    for (int r = 0; r < 2; ++r) { \
      int s    = r * 256 + tid; \
      int row  = s >> 4; \
      int cpos = s & 15; \
      int cg   = cpos ^ ((row & 7) << 1); \
      GLOAD_LDS(x + (size_t)(r0 + row) * CC + (KS) * 64 + cg * 4, \
                &xbuf[BUF][s * 16]); \
    } }

  // W fragments straight to registers (contiguous per wave)
#define LW(KS, WD) { \
    _Pragma("unroll") \
    for (int ktl = 0; ktl < 2; ++ktl) \
      _Pragma("unroll") \
      for (int j = 0; j < 3; ++j) \
        WD[ktl][j] = *(const bf16x8*)(wp + \
            ((size_t)((KS) * 24 + ktl * 12 + cq * 3 + j) * 64 + l) * 8); }

  // compute one K-step from xbuf[BUF] with W regs WD
#define COMP(BUF, WD) { \
    _Pragma("unroll") \
    for (int ktl = 0; ktl < 2; ++ktl) { \
      bf16x8 afr[2]; \
      _Pragma("unroll") \
      for (int g = 0; g < 2; ++g) { \
        int row = g * 16 + rl; \
        int sw  = (row & 7) << 1; \
        int c0  = ktl * 8 + hi * 2; \
        const unsigned char* rb = &xbuf[BUF][row * 256]; \
        f32x4 a0 = *(const f32x4*)(rb + ((c0 ^ sw) * 16)); \
        f32x4 a1 = *(const f32x4*)(rb + (((c0 + 1) ^ sw) * 16)); \
        bf16x8 af; \
        af[0] = (short)f2b(a0[0]); af[1] = (short)f2b(a0[1]); \
        af[2] = (short)f2b(a0[2]); af[3] = (short)f2b(a0[3]); \
        af[4] = (short)f2b(a1[0]); af[5] = (short)f2b(a1[1]); \
        af[6] = (short)f2b(a1[2]); af[7] = (short)f2b(a1[3]); \
        afr[g] = af; \
      } \
      _Pragma("unroll") \
      for (int j = 0; j < 3; ++j) { \
        acc[0][j] = MFMA16(afr[0], WD[ktl][j], acc[0][j]); \
        acc[1][j] = MFMA16(afr[1], WD[ktl][j], acc[1][j]); \
      } \
    } }

#define PHASE_WAIT(N) { \
    asm volatile("s_waitcnt vmcnt(" #N ")" ::: "memory"); \
    __builtin_amdgcn_sched_barrier(0); \
    __builtin_amdgcn_s_barrier(); }

#define PHASE_END { \
    asm volatile("s_waitcnt lgkmcnt(0)" ::: "memory"); \
    __builtin_amdgcn_sched_barrier(0); \
    __builtin_amdgcn_s_barrier(); }

  bf16x8 wA[2][3], wB[2][3];

  SX(0, 0) SX(1, 1) SX(2, 2)
  LW(0, wA) LW(1, wB)

  #pragma unroll 1
  for (int ks = 0; ks < 16; ks += 2) {
    const int bufA = ks % 3;
    const int bufB = (ks + 1) % 3;
    // ---- even step: xbuf[bufA], wA ----
    PHASE_WAIT(6)
    COMP(bufA, wA)
    PHASE_END
    if (ks + 3 <= 15) { SX(ks + 3, (ks + 3) % 3) }
    if (ks + 2 <= 15) { LW(ks + 2, wA) }
    __builtin_amdgcn_sched_barrier(0);
    // ---- odd step: xbuf[bufB], wB ----
    if (ks + 1 < 15) { PHASE_WAIT(6) } else { PHASE_WAIT(0) }
    COMP(bufB, wB)
    PHASE_END
    if (ks + 4 <= 15) { SX(ks + 4, (ks + 4) % 3) }
    if (ks + 3 <= 15) { LW(ks + 3, wB) }
    __builtin_amdgcn_sched_barrier(0);
  }
#undef SX
#undef LW
#undef COMP
#undef PHASE_WAIT
#undef PHASE_END

  // ---- store: nb 0..3 -> q, 4..7 -> k, 8..11 -> v (transposed per 64-chunk)
  #pragma unroll
  for (int g = 0; g < 2; ++g) {
    int rb = r0 + g * 16;
    #pragma unroll
    for (int j = 0; j < 3; ++j) {
      int nb = cq * 3 + j;
      if (nb < 8) {
        unsigned short* dst = (nb < 4) ? q_ws : k_ws;
        int c = (nb & 3) * 16 + rl;
        #pragma unroll
        for (int r = 0; r < 4; ++r) {
          int row = rb + hi * 4 + r;
          dst[(size_t)row * HS + c] = f2b(acc[g][j][r]);
        }
      } else {
        int ch   = rb >> 6;
        int key0 = (rb & 63) + hi * 4;
        int d = (nb - 8) * 16 + rl;
        unsigned u0 = (unsigned)f2b(acc[g][j][0]) | ((unsigned)f2b(acc[g][j][1]) << 16);
        unsigned u1 = (unsigned)f2b(acc[g][j][2]) | ((unsigned)f2b(acc[g][j][3]) << 16);
        uint2 uu; uu.x = u0; uu.y = u1;
        *(uint2*)(vt_ws + (size_t)ch * 4096 + d * 64 + key0) = uu;
      }
    }
  }
}

// ---------------- Sliding-window flash attention via MFMA ----------------
// grid 256 blocks (b, 64-q tile) x 256 threads (4 waves, 16 q-rows each).
// Swapped QK^T (S^T = K @ Q^T) -> softmax lane-local; P via wave-private LDS;
// PV with V^T staged swizzled.
__global__ __launch_bounds__(256) void attn_mfma_kernel(
    const unsigned short* __restrict__ q_ws, const unsigned short* __restrict__ k_ws,
    const unsigned short* __restrict__ vt_ws, float* __restrict__ out)
{
  __shared__ uint4 smem4[1600];                 // 25600 B
  unsigned char* smem = (unsigned char*)smem4;  // K:[0,8K) Vt:[8K,16K) P:16K+

  const int tid = threadIdx.x;
  const int l   = tid & 63;
  const int wid = tid >> 6;
  const int rl  = l & 15;
  const int hi  = l >> 4;
  const int b   = blockIdx.x >> 6;
  const int qt  = blockIdx.x & 63;
  const int t0  = qt * 64;
  const int t0w = t0 + wid * 16;

  // Q B-fragments (held in registers): lane = q row t0w+rl, d = hi*8+j (+32)
  const unsigned short* qrow = q_ws + (size_t)(b * TT + t0w + rl) * HS;
  bf16x8 qb0 = *(const bf16x8*)(qrow + hi * 8);
  bf16x8 qb1 = *(const bf16x8*)(qrow + 32 + hi * 8);

  f32x4 oacc[4];
  #pragma unroll
  for (int i = 0; i < 4; ++i) oacc[i] = (f32x4){0.f, 0.f, 0.f, 0.f};
  float m_run = -INFINITY, l_run = 0.f;

  int s_lo = t0 - WIN; if (s_lo < 0) s_lo = 0;
  unsigned char* pbase = smem + 16384 + wid * 2304 + rl * 144;

  for (int sc = s_lo; sc < t0 + 64; sc += 64) {
    __syncthreads();
    // ---- stage K and Vt chunk (64x64 bf16 each), XOR-swizzled rows ----
    {
      const unsigned short* kg = k_ws + (size_t)(b * TT + sc) * HS;
      const unsigned short* vg = vt_ws + (size_t)((b * TT + sc) >> 6) * 4096;
      #pragma unroll
      for (int i = 0; i < 2; ++i) {
        int idx = tid + i * 256;
        int row = idx >> 3;
        int c16 = idx & 7;
        uint4 kv = *(const uint4*)(kg + row * 64 + c16 * 8);
        uint4 vv = *(const uint4*)(vg + row * 64 + c16 * 8);
        *(uint4*)(smem + row * 128 + ((c16 ^ (row & 7)) * 16)) = kv;
        *(uint4*)(smem + 8192 + row * 128 + ((c16 ^ (row & 7)) * 16)) = vv;
      }
    }
    __syncthreads();

    // ---- S^T = K @ Q^T : 4 key-block fragments ----
    f32x4 sacc[4];
    #pragma unroll
    for (int i = 0; i < 4; ++i) sacc[i] = (f32x4){0.f, 0.f, 0.f, 0.f};
    #pragma unroll
    for (int kb = 0; kb < 4; ++kb) {
      int row = kb * 16 + rl;
      unsigned char* kr = smem + row * 128;
      bf16x8 k0 = *(const bf16x8*)(kr + (((hi) ^ (row & 7)) * 16));
      bf16x8 k1 = *(const bf16x8*)(kr + (((4 + hi) ^ (row & 7)) * 16));
      sacc[kb] = MFMA16(k0, qb0, sacc[kb]);
      sacc[kb] = MFMA16(k1, qb1, sacc[kb]);
    }

    // ---- mask + scale + online softmax (lane owns one q = t0w+rl) ----
    const int tg = t0w + rl;
    float p[16];
    float tm = -INFINITY;
    bool full = (sc + 63 <= t0w) && (sc >= t0w - 496);
    #pragma unroll
    for (int kb = 0; kb < 4; ++kb)
      #pragma unroll
      for (int r = 0; r < 4; ++r) {
        float v = sacc[kb][r] * 0.125f;
        if (!full) {
          int key = sc + kb * 16 + hi * 4 + r;
          int diff = tg - key;
          v = (diff >= 0 && diff < WIN) ? v : -INFINITY;
        }
        p[kb * 4 + r] = v;
        tm = fmaxf(tm, v);
      }
    tm = fmaxf(tm, __shfl_xor(tm, 16));
    tm = fmaxf(tm, __shfl_xor(tm, 32));
    float m_new = fmaxf(m_run, tm);
    float fac  = (m_new == -INFINITY) ? 1.f : __expf(m_run - m_new);
    float msub = (m_new == -INFINITY) ? 0.f : m_new;
    float lsum = 0.f;
    #pragma unroll
    for (int i = 0; i < 16; ++i) { p[i] = __expf(p[i] - msub); lsum += p[i]; }
    lsum += __shfl_xor(lsum, 16);
    lsum += __shfl_xor(lsum, 32);
    l_run = l_run * fac + lsum;
    m_run = m_new;

    // ---- P -> wave-private LDS (row q=rl, stride 144 B) ----
    #pragma unroll
    for (int kb = 0; kb < 4; ++kb) {
      unsigned u0 = (unsigned)f2b(p[kb * 4 + 0]) | ((unsigned)f2b(p[kb * 4 + 1]) << 16);
      unsigned u1 = (unsigned)f2b(p[kb * 4 + 2]) | ((unsigned)f2b(p[kb * 4 + 3]) << 16);
      uint2 uu; uu.x = u0; uu.y = u1;
      *(uint2*)(pbase + kb * 32 + hi * 8) = uu;
    }

    // ---- rescale O by fac (redistribute to PV C-layout q = hi*4+r) ----
    #pragma unroll
    for (int r = 0; r < 4; ++r) {
      float fr = __shfl(fac, (l & 48) | (hi * 4 + r));
      oacc[0][r] *= fr; oacc[1][r] *= fr; oacc[2][r] *= fr; oacc[3][r] *= fr;
    }

    // ---- PV: O[q][d] += P @ V ----
    bf16x8 pa0 = *(const bf16x8*)(pbase + hi * 16);
    bf16x8 pa1 = *(const bf16x8*)(pbase + 64 + hi * 16);
    #pragma unroll
    for (int f = 0; f < 4; ++f) {
      int d = f * 16 + rl;
      unsigned char* vr = smem + 8192 + d * 128;
      bf16x8 v0 = *(const bf16x8*)(vr + (((hi) ^ (d & 7)) * 16));
      bf16x8 v1 = *(const bf16x8*)(vr + (((4 + hi) ^ (d & 7)) * 16));
      oacc[f] = MFMA16(pa0, v0, oacc[f]);
      oacc[f] = MFMA16(pa1, v1, oacc[f]);
    }
  }

  // ---- epilogue: normalize and store f32 ----
  float inv = 1.f / l_run;   // softmax layout (q = rl)
  #pragma unroll
  for (int r = 0; r < 4; ++r) {
    float ir = __shfl(inv, (l & 48) | (hi * 4 + r));
    int row = b * TT + t0w + hi * 4 + r;
    #pragma unroll
    for (int f = 0; f < 4; ++f)
      out[(size_t)row * HS + f * 16 + rl] = oacc[f][r] * ir;
  }
}

extern "C" void kernel_launch(void* const* d_in, const int* in_sizes, int n_in,
                              void* d_out, int out_size, void* d_ws, size_t ws_size,
                              hipStream_t stream) {
  // setup_inputs dict order: x, w_key, w_query, w_value
  const float* x  = (const float*)d_in[0];
  const float* wk = (const float*)d_in[1];
  const float* wq = (const float*)d_in[2];
  const float* wv = (const float*)d_in[3];
  float* out = (float*)d_out;

  unsigned short* wp    = (unsigned short*)d_ws;        // 196608 el = 384 KB
  unsigned short* q_ws  = wp + 196608;                  // 2 MB
  unsigned short* k_ws  = q_ws + (size_t)NROW * HS;     // 2 MB
  unsigned short* vt_ws = k_ws + (size_t)NROW * HS;     // 2 MB

  pack_w_kernel<<<192, 256, 0, stream>>>(wq, wk, wv, wp);
  proj_mfma_kernel<<<NROW / 32, 256, 0, stream>>>(x, wp, q_ws, k_ws, vt_ws);
  attn_mfma_kernel<<<BB * (TT / 64), 256, 0, stream>>>(q_ws, k_ws, vt_ws, out);
}